// Round 1
// baseline (344.619 us; speedup 1.0000x reference)
//
#include <hip/hip_runtime.h>

typedef __attribute__((ext_vector_type(8))) __bf16 bf16x8;
typedef __attribute__((ext_vector_type(4))) __bf16 bf16x4;
typedef __attribute__((ext_vector_type(4))) float f32x4;

static constexpr int S = 2048;
static constexpr int D = 1024;
static constexpr int H = 16;
static constexpr int BATCH = 2;
static constexpr int M_ROWS = BATCH * S;  // 4096

// ---------------- f32 -> bf16 cast ----------------
__global__ __launch_bounds__(256) void cast_f32_bf16(const float* __restrict__ in,
                                                     __bf16* __restrict__ out, int n) {
  int i = (blockIdx.x * 256 + threadIdx.x) * 4;
  if (i >= n) return;
  f32x4 v = *reinterpret_cast<const f32x4*>(in + i);
  bf16x4 o = __builtin_convertvector(v, bf16x4);
  *reinterpret_cast<bf16x4*>(out + i) = o;
}

// ---------------- C[M,N] = A[M,K] @ B[N,K]^T ----------------
// 128x128 tile, 4 waves (2x2), each wave 64x64 = 4x4 fragments of 16x16.
template <typename OutT>
__global__ __launch_bounds__(256) void gemm_bt(const __bf16* __restrict__ A,
                                               const __bf16* __restrict__ Bm,
                                               OutT* __restrict__ C,
                                               int Mm, int Nn, int K) {
  __shared__ __bf16 At[128][40];  // +8 pad: row stride 80B, 16B-aligned, kills pow2 stride
  __shared__ __bf16 Bt[128][40];
  const int m0 = blockIdx.y * 128, n0 = blockIdx.x * 128;
  const int tid = threadIdx.x;
  const int w = tid >> 6, l = tid & 63;
  const int wr = w >> 1, wc = w & 1;
  const int ln = l & 15, gr = l >> 4;

  f32x4 acc[4][4] = {};

  for (int k0 = 0; k0 < K; k0 += 32) {
    __syncthreads();
#pragma unroll
    for (int i = 0; i < 2; i++) {
      int c = tid + i * 256;           // 512 chunks of 8 bf16 per tile
      int r = c >> 2, cc = (c & 3) * 8;
      *reinterpret_cast<bf16x8*>(&At[r][cc]) =
          *reinterpret_cast<const bf16x8*>(A + (size_t)(m0 + r) * K + k0 + cc);
      *reinterpret_cast<bf16x8*>(&Bt[r][cc]) =
          *reinterpret_cast<const bf16x8*>(Bm + (size_t)(n0 + r) * K + k0 + cc);
    }
    __syncthreads();

    bf16x8 af[4], bfr[4];
#pragma unroll
    for (int mi = 0; mi < 4; mi++)
      af[mi] = *reinterpret_cast<const bf16x8*>(&At[wr * 64 + mi * 16 + ln][gr * 8]);
#pragma unroll
    for (int ni = 0; ni < 4; ni++)
      bfr[ni] = *reinterpret_cast<const bf16x8*>(&Bt[wc * 64 + ni * 16 + ln][gr * 8]);
#pragma unroll
    for (int mi = 0; mi < 4; mi++)
#pragma unroll
      for (int ni = 0; ni < 4; ni++)
        acc[mi][ni] = __builtin_amdgcn_mfma_f32_16x16x32_bf16(af[mi], bfr[ni], acc[mi][ni], 0, 0, 0);
  }

#pragma unroll
  for (int mi = 0; mi < 4; mi++)
#pragma unroll
    for (int ni = 0; ni < 4; ni++)
#pragma unroll
      for (int r = 0; r < 4; r++) {
        int row = m0 + wr * 64 + mi * 16 + gr * 4 + r;
        int col = n0 + wc * 64 + ni * 16 + ln;
        float v = acc[mi][ni][r];
        if constexpr (__is_same(OutT, float))
          C[(size_t)row * Nn + col] = v;
        else
          C[(size_t)row * Nn + col] = (__bf16)v;
      }
}

// ---------------- causal flash attention ----------------
// grid: (S/64, B*H). block: 256 = 4 waves; wave w owns q rows [q0+16w, q0+16w+16).
// K/V chunk of 32 staged in LDS per iteration (V transposed).
__global__ __launch_bounds__(256) void attn_kernel(const __bf16* __restrict__ Qb,
                                                   const __bf16* __restrict__ Kb,
                                                   const __bf16* __restrict__ Vb,
                                                   __bf16* __restrict__ Ob) {
  __shared__ __bf16 kt[32][64];      // [kk][d]
  __shared__ __bf16 vt[64][32];      // transposed: [d][kk]
  __shared__ __bf16 pt[4][16][32];   // per-wave P tile [q][kk]

  const int bh = blockIdx.y;
  const int b = bh >> 4, h = bh & 15;
  const int q0 = blockIdx.x * 64;
  const __bf16* Q = Qb + (size_t)b * S * D + h * 64;
  const __bf16* Kp = Kb + (size_t)b * S * D + h * 64;
  const __bf16* Vp = Vb + (size_t)b * S * D + h * 64;

  const int tid = threadIdx.x;
  const int w = tid >> 6, l = tid & 63;
  const int ln = l & 15, gr = l >> 4;
  const int qrow_base = q0 + w * 16;
  const float SCALE = 0.125f;  // 1/sqrt(64)
  const float NEG = -1e30f;

  bf16x8 qf[2];
#pragma unroll
  for (int s = 0; s < 2; s++)
    qf[s] = *reinterpret_cast<const bf16x8*>(Q + (size_t)(qrow_base + ln) * D + s * 32 + gr * 8);

  f32x4 oacc[4] = {};
  float mr[4] = {NEG, NEG, NEG, NEG};
  float ls[4] = {0.f, 0.f, 0.f, 0.f};

  const int kend = q0 + 63;
  for (int k0 = 0; k0 <= kend; k0 += 32) {
    // ---- stage K and V(transposed) chunk ----
    {
      int r = tid >> 3, c8 = (tid & 7) * 8;
      bf16x8 kv = *reinterpret_cast<const bf16x8*>(Kp + (size_t)(k0 + r) * D + c8);
      *reinterpret_cast<bf16x8*>(&kt[r][c8]) = kv;
      bf16x8 vv = *reinterpret_cast<const bf16x8*>(Vp + (size_t)(k0 + r) * D + c8);
#pragma unroll
      for (int j = 0; j < 8; j++) vt[c8 + j][r] = vv[j];
    }
    __syncthreads();

    // ---- S = Q K^T for 2 tiles of 16 kk-cols ----
    f32x4 sacc[2];
#pragma unroll
    for (int c = 0; c < 2; c++) {
      f32x4 z = {};
      bf16x8 kf0 = *reinterpret_cast<const bf16x8*>(&kt[c * 16 + ln][gr * 8]);
      bf16x8 kf1 = *reinterpret_cast<const bf16x8*>(&kt[c * 16 + ln][32 + gr * 8]);
      z = __builtin_amdgcn_mfma_f32_16x16x32_bf16(qf[0], kf0, z, 0, 0, 0);
      z = __builtin_amdgcn_mfma_f32_16x16x32_bf16(qf[1], kf1, z, 0, 0, 0);
      sacc[c] = z;
    }

    // ---- online softmax (per q-row; rows live in regs r, cols across 16-lane group) ----
#pragma unroll
    for (int r = 0; r < 4; r++) {
      int q = qrow_base + gr * 4 + r;
      float s0 = (k0 + ln <= q) ? sacc[0][r] * SCALE : NEG;
      float s1 = (k0 + 16 + ln <= q) ? sacc[1][r] * SCALE : NEG;
      float tm = fmaxf(s0, s1);
#pragma unroll
      for (int msk = 1; msk < 16; msk <<= 1) tm = fmaxf(tm, __shfl_xor(tm, msk, 16));
      float nm = fmaxf(mr[r], tm);
      float al = __expf(mr[r] - nm);
      float p0 = __expf(s0 - nm);
      float p1 = __expf(s1 - nm);
      float ps = p0 + p1;
#pragma unroll
      for (int msk = 1; msk < 16; msk <<= 1) ps += __shfl_xor(ps, msk, 16);
      ls[r] = ls[r] * al + ps;
      mr[r] = nm;
#pragma unroll
      for (int t = 0; t < 4; t++) oacc[t][r] *= al;
      pt[w][gr * 4 + r][ln] = (__bf16)p0;
      pt[w][gr * 4 + r][16 + ln] = (__bf16)p1;
    }

    // ---- O += P V ----
    bf16x8 pa = *reinterpret_cast<const bf16x8*>(&pt[w][ln][gr * 8]);
#pragma unroll
    for (int t = 0; t < 4; t++) {
      bf16x8 vb = *reinterpret_cast<const bf16x8*>(&vt[t * 16 + ln][gr * 8]);
      oacc[t] = __builtin_amdgcn_mfma_f32_16x16x32_bf16(pa, vb, oacc[t], 0, 0, 0);
    }
    __syncthreads();
  }

  // ---- normalize + store ----
#pragma unroll
  for (int r = 0; r < 4; r++) {
    float inv = 1.0f / ls[r];
    size_t row = (size_t)(b * S + qrow_base + gr * 4 + r);
#pragma unroll
    for (int t = 0; t < 4; t++)
      Ob[row * D + h * 64 + t * 16 + ln] = (__bf16)(oacc[t][r] * inv);
  }
}

// ---------------- launcher ----------------
extern "C" void kernel_launch(void* const* d_in, const int* in_sizes, int n_in,
                              void* d_out, int out_size, void* d_ws, size_t ws_size,
                              hipStream_t stream) {
  const float* x = (const float*)d_in[0];
  const float* Wq = (const float*)d_in[1];
  const float* Wk = (const float*)d_in[2];
  const float* Wv = (const float*)d_in[3];
  const float* Wo = (const float*)d_in[4];
  float* out = (float*)d_out;

  char* ws = (char*)d_ws;
  const size_t MB = 1024 * 1024;
  __bf16* xb = (__bf16*)(ws + 0 * MB);    // 8 MB
  __bf16* qb = (__bf16*)(ws + 8 * MB);    // 8 MB
  __bf16* kb = (__bf16*)(ws + 16 * MB);   // 8 MB
  __bf16* vb = (__bf16*)(ws + 24 * MB);   // 8 MB
  __bf16* ob = (__bf16*)(ws + 32 * MB);   // 8 MB
  __bf16* wqb = (__bf16*)(ws + 40 * MB);  // 2 MB
  __bf16* wkb = (__bf16*)(ws + 42 * MB);
  __bf16* wvb = (__bf16*)(ws + 44 * MB);
  __bf16* wob = (__bf16*)(ws + 46 * MB);

  const int nx = M_ROWS * D;   // 4,194,304
  const int nw = D * D;        // 1,048,576

  cast_f32_bf16<<<nx / 4 / 256, 256, 0, stream>>>(x, xb, nx);
  cast_f32_bf16<<<nw / 4 / 256, 256, 0, stream>>>(Wq, wqb, nw);
  cast_f32_bf16<<<nw / 4 / 256, 256, 0, stream>>>(Wk, wkb, nw);
  cast_f32_bf16<<<nw / 4 / 256, 256, 0, stream>>>(Wv, wvb, nw);
  cast_f32_bf16<<<nw / 4 / 256, 256, 0, stream>>>(Wo, wob, nw);

  dim3 ggrid(D / 128, M_ROWS / 128);  // (8, 32)
  gemm_bt<__bf16><<<ggrid, 256, 0, stream>>>(xb, wqb, qb, M_ROWS, D, D);
  gemm_bt<__bf16><<<ggrid, 256, 0, stream>>>(xb, wkb, kb, M_ROWS, D, D);
  gemm_bt<__bf16><<<ggrid, 256, 0, stream>>>(xb, wvb, vb, M_ROWS, D, D);

  attn_kernel<<<dim3(S / 64, BATCH * H), 256, 0, stream>>>(qb, kb, vb, ob);

  gemm_bt<float><<<ggrid, 256, 0, stream>>>(ob, wob, out, M_ROWS, D, D);
}

// Round 3
// 228.220 us; speedup vs baseline: 1.5100x; 1.5100x over previous
//
#include <hip/hip_runtime.h>

typedef __attribute__((ext_vector_type(8))) __bf16 bf16x8;
typedef __attribute__((ext_vector_type(4))) __bf16 bf16x4;
typedef __attribute__((ext_vector_type(4))) float f32x4;

static constexpr int S = 2048;
static constexpr int D = 1024;
static constexpr int BATCH = 2;
static constexpr int M_ROWS = BATCH * S;  // 4096

#define GLOAD_LDS16(gp, lp)                                                        \
  __builtin_amdgcn_global_load_lds((const __attribute__((address_space(1))) void*)(gp), \
                                   (__attribute__((address_space(3))) void*)(lp), 16, 0, 0)

// ---------------- f32 -> bf16 casts ----------------
__global__ __launch_bounds__(256) void cast_f32_bf16(const float* __restrict__ in,
                                                     __bf16* __restrict__ out) {
  int i = (blockIdx.x * 256 + threadIdx.x) * 4;
  *reinterpret_cast<bf16x4*>(out + i) =
      __builtin_convertvector(*reinterpret_cast<const f32x4*>(in + i), bf16x4);
}

__global__ __launch_bounds__(256) void cast_w4(const float* __restrict__ w0, const float* __restrict__ w1,
                                               const float* __restrict__ w2, const float* __restrict__ w3,
                                               __bf16* __restrict__ o0, __bf16* __restrict__ o1,
                                               __bf16* __restrict__ o2, __bf16* __restrict__ o3) {
  const float* in = blockIdx.y == 0 ? w0 : blockIdx.y == 1 ? w1 : blockIdx.y == 2 ? w2 : w3;
  __bf16* out = blockIdx.y == 0 ? o0 : blockIdx.y == 1 ? o1 : blockIdx.y == 2 ? o2 : o3;
  int i = (blockIdx.x * 256 + threadIdx.x) * 4;
  *reinterpret_cast<bf16x4*>(out + i) =
      __builtin_convertvector(*reinterpret_cast<const f32x4*>(in + i), bf16x4);
}

// ---------------- C[M,N] = A[M,K] @ B[N,K]^T (m97 structure) ----------------
// 128x128 tile, BK=32, 4 waves (2x2), global_load_lds width-16 staging, linear LDS.
// blockIdx.z selects among up to 3 (B, C) pairs (fused QKV).
template <typename OutT>
__global__ __launch_bounds__(256) void gemm_bt(const __bf16* __restrict__ A,
                                               const __bf16* __restrict__ B0,
                                               const __bf16* __restrict__ B1,
                                               const __bf16* __restrict__ B2,
                                               OutT* __restrict__ C0, OutT* __restrict__ C1,
                                               OutT* __restrict__ C2, int K, int Nn) {
  __shared__ __bf16 At[128 * 32];
  __shared__ __bf16 Bt[128 * 32];
  const __bf16* Bm = blockIdx.z == 0 ? B0 : blockIdx.z == 1 ? B1 : B2;
  OutT* C = blockIdx.z == 0 ? C0 : blockIdx.z == 1 ? C1 : C2;

  const int m0 = blockIdx.y * 128, n0 = blockIdx.x * 128;
  const int tid = threadIdx.x;
  const int w = tid >> 6, l = tid & 63;
  const int wr = w >> 1, wc = w & 1;
  const int ln = l & 15, gr = l >> 4;

  // staging: 8 wave-instructions of 1KB cover one 128x32 tile; wave w issues 2.
  const int srow = w * 32 + (l >> 2);
  const int scol = (l & 3) * 8;
  const size_t aoff = (size_t)(m0 + srow) * K + scol;
  const size_t boff = (size_t)(n0 + srow) * K + scol;
  __bf16* lA = At + w * 2 * 512;  // 512 elements = 1024B per issue
  __bf16* lB = Bt + w * 2 * 512;

  f32x4 acc[4][4] = {};

  for (int k0 = 0; k0 < K; k0 += 32) {
    __syncthreads();
    GLOAD_LDS16(A + aoff + k0, lA);
    GLOAD_LDS16(A + aoff + (size_t)16 * K + k0, lA + 512);
    GLOAD_LDS16(Bm + boff + k0, lB);
    GLOAD_LDS16(Bm + boff + (size_t)16 * K + k0, lB + 512);
    __syncthreads();

    bf16x8 af[4], bfr[4];
#pragma unroll
    for (int mi = 0; mi < 4; mi++)
      af[mi] = *reinterpret_cast<const bf16x8*>(&At[(wr * 64 + mi * 16 + ln) * 32 + gr * 8]);
#pragma unroll
    for (int ni = 0; ni < 4; ni++)
      bfr[ni] = *reinterpret_cast<const bf16x8*>(&Bt[(wc * 64 + ni * 16 + ln) * 32 + gr * 8]);
#pragma unroll
    for (int mi = 0; mi < 4; mi++)
#pragma unroll
      for (int ni = 0; ni < 4; ni++)
        acc[mi][ni] = __builtin_amdgcn_mfma_f32_16x16x32_bf16(af[mi], bfr[ni], acc[mi][ni], 0, 0, 0);
  }

#pragma unroll
  for (int mi = 0; mi < 4; mi++)
#pragma unroll
    for (int ni = 0; ni < 4; ni++)
#pragma unroll
      for (int r = 0; r < 4; r++) {
        int row = m0 + wr * 64 + mi * 16 + gr * 4 + r;
        int col = n0 + wc * 64 + ni * 16 + ln;
        float v = acc[mi][ni][r];
        if constexpr (__is_same(OutT, float))
          C[(size_t)row * Nn + col] = v;
        else
          C[(size_t)row * Nn + col] = (__bf16)v;
      }
}

// ---------------- causal flash attention ----------------
// grid: (S/128, B*H). block: 256 = 4 waves; wave w owns q rows [q0+32w, q0+32w+32).
// KVBLK=64 staged in LDS (V transposed via packed b64 writes). Row stride 72
// elements = 144B: 16B-aligned for ds_read_b128, 2-way bank aliasing (free).
__global__ __launch_bounds__(256) void attn_kernel(const __bf16* __restrict__ Qb,
                                                   const __bf16* __restrict__ Kb,
                                                   const __bf16* __restrict__ Vb,
                                                   __bf16* __restrict__ Ob) {
  __shared__ __bf16 kt[64][72];      // [key][d]
  __shared__ __bf16 vt[64][72];      // transposed: [d][key]
  __shared__ __bf16 pt[4][32][72];   // per-wave P tile [q][key]

  const int bh = blockIdx.y;
  const int b = bh >> 4, h = bh & 15;
  const int q0 = blockIdx.x * 128;
  const __bf16* Qp = Qb + (size_t)b * S * D + h * 64;
  const __bf16* Kp = Kb + (size_t)b * S * D + h * 64;
  const __bf16* Vp = Vb + (size_t)b * S * D + h * 64;

  const int tid = threadIdx.x;
  const int w = tid >> 6, l = tid & 63;
  const int ln = l & 15, gr = l >> 4;
  const int qbase = q0 + w * 32;
  const float SCALE = 0.125f;  // 1/sqrt(64)
  const float NEG = -1e30f;

  // staging coords
  const int kr = tid >> 3, kc = (tid & 7) * 8;  // K: rows kr, kr+32; 8 cols
  const int rq = tid >> 4, c4 = tid & 15;       // V: 4 rows x 4 cols micro-tile

  bf16x8 qf[2][2];
#pragma unroll
  for (int m = 0; m < 2; m++)
#pragma unroll
    for (int s = 0; s < 2; s++)
      qf[m][s] = *reinterpret_cast<const bf16x8*>(
          Qp + (size_t)(qbase + m * 16 + ln) * D + s * 32 + gr * 8);

  f32x4 oacc[2][4] = {};
  float mr[2][4], ls[2][4];
#pragma unroll
  for (int m = 0; m < 2; m++)
#pragma unroll
    for (int r = 0; r < 4; r++) { mr[m][r] = NEG; ls[m][r] = 0.f; }

  const int kmax = q0 + 128;
  for (int k0 = 0; k0 < kmax; k0 += 64) {
    __syncthreads();
    // ---- stage K ----
    *reinterpret_cast<bf16x8*>(&kt[kr][kc]) =
        *reinterpret_cast<const bf16x8*>(Kp + (size_t)(k0 + kr) * D + kc);
    *reinterpret_cast<bf16x8*>(&kt[kr + 32][kc]) =
        *reinterpret_cast<const bf16x8*>(Kp + (size_t)(k0 + kr + 32) * D + kc);
    // ---- stage V transposed: 4x4 micro-tile, packed b64 column writes ----
    {
      bf16x4 v0 = *reinterpret_cast<const bf16x4*>(Vp + (size_t)(k0 + rq * 4 + 0) * D + c4 * 4);
      bf16x4 v1 = *reinterpret_cast<const bf16x4*>(Vp + (size_t)(k0 + rq * 4 + 1) * D + c4 * 4);
      bf16x4 v2 = *reinterpret_cast<const bf16x4*>(Vp + (size_t)(k0 + rq * 4 + 2) * D + c4 * 4);
      bf16x4 v3 = *reinterpret_cast<const bf16x4*>(Vp + (size_t)(k0 + rq * 4 + 3) * D + c4 * 4);
#pragma unroll
      for (int jj = 0; jj < 4; jj++) {
        bf16x4 pk = {v0[jj], v1[jj], v2[jj], v3[jj]};
        *reinterpret_cast<bf16x4*>(&vt[c4 * 4 + jj][rq * 4]) = pk;
      }
    }
    __syncthreads();

    // ---- S = Q K^T ----
    f32x4 sacc[2][4] = {};
#pragma unroll
    for (int c = 0; c < 4; c++) {
      bf16x8 kf0 = *reinterpret_cast<const bf16x8*>(&kt[c * 16 + ln][gr * 8]);
      bf16x8 kf1 = *reinterpret_cast<const bf16x8*>(&kt[c * 16 + ln][32 + gr * 8]);
#pragma unroll
      for (int m = 0; m < 2; m++) {
        sacc[m][c] = __builtin_amdgcn_mfma_f32_16x16x32_bf16(qf[m][0], kf0, sacc[m][c], 0, 0, 0);
        sacc[m][c] = __builtin_amdgcn_mfma_f32_16x16x32_bf16(qf[m][1], kf1, sacc[m][c], 0, 0, 0);
      }
    }

    // ---- online softmax (8 rows/wave; 16-lane group reduces) ----
    const bool needmask = (k0 + 63 > qbase);
#pragma unroll
    for (int m = 0; m < 2; m++)
#pragma unroll
      for (int r = 0; r < 4; r++) {
        const int q = qbase + m * 16 + gr * 4 + r;
        float sv[4];
#pragma unroll
        for (int c = 0; c < 4; c++) {
          int key = k0 + c * 16 + ln;
          sv[c] = (!needmask || key <= q) ? sacc[m][c][r] * SCALE : NEG;
        }
        float tm = fmaxf(fmaxf(sv[0], sv[1]), fmaxf(sv[2], sv[3]));
#pragma unroll
        for (int msk = 1; msk < 16; msk <<= 1) tm = fmaxf(tm, __shfl_xor(tm, msk, 16));
        float nm = fmaxf(mr[m][r], tm);
        float al = __expf(mr[m][r] - nm);
        mr[m][r] = nm;
        float p[4], ps = 0.f;
#pragma unroll
        for (int c = 0; c < 4; c++) { p[c] = __expf(sv[c] - nm); ps += p[c]; }
#pragma unroll
        for (int msk = 1; msk < 16; msk <<= 1) ps += __shfl_xor(ps, msk, 16);
        ls[m][r] = ls[m][r] * al + ps;
#pragma unroll
        for (int t = 0; t < 4; t++) oacc[m][t][r] *= al;
#pragma unroll
        for (int c = 0; c < 4; c++) pt[w][m * 16 + gr * 4 + r][c * 16 + ln] = (__bf16)p[c];
      }

    // ---- O += P V ----
#pragma unroll
    for (int ks = 0; ks < 2; ks++) {
      bf16x8 pa0 = *reinterpret_cast<const bf16x8*>(&pt[w][ln][ks * 32 + gr * 8]);
      bf16x8 pa1 = *reinterpret_cast<const bf16x8*>(&pt[w][16 + ln][ks * 32 + gr * 8]);
#pragma unroll
      for (int t = 0; t < 4; t++) {
        bf16x8 vb = *reinterpret_cast<const bf16x8*>(&vt[t * 16 + ln][ks * 32 + gr * 8]);
        oacc[0][t] = __builtin_amdgcn_mfma_f32_16x16x32_bf16(pa0, vb, oacc[0][t], 0, 0, 0);
        oacc[1][t] = __builtin_amdgcn_mfma_f32_16x16x32_bf16(pa1, vb, oacc[1][t], 0, 0, 0);
      }
    }
  }

  // ---- normalize + store ----
#pragma unroll
  for (int m = 0; m < 2; m++)
#pragma unroll
    for (int r = 0; r < 4; r++) {
      float inv = 1.0f / ls[m][r];
      size_t row = (size_t)(b * S + qbase + m * 16 + gr * 4 + r);
#pragma unroll
      for (int t = 0; t < 4; t++)
        Ob[row * D + h * 64 + t * 16 + ln] = (__bf16)(oacc[m][t][r] * inv);
    }
}

// ---------------- launcher ----------------
extern "C" void kernel_launch(void* const* d_in, const int* in_sizes, int n_in,
                              void* d_out, int out_size, void* d_ws, size_t ws_size,
                              hipStream_t stream) {
  const float* x = (const float*)d_in[0];
  const float* Wq = (const float*)d_in[1];
  const float* Wk = (const float*)d_in[2];
  const float* Wv = (const float*)d_in[3];
  const float* Wo = (const float*)d_in[4];
  float* out = (float*)d_out;

  char* ws = (char*)d_ws;
  const size_t MB = 1024 * 1024;
  __bf16* xb = (__bf16*)(ws + 0 * MB);
  __bf16* qb = (__bf16*)(ws + 8 * MB);
  __bf16* kb = (__bf16*)(ws + 16 * MB);
  __bf16* vb = (__bf16*)(ws + 24 * MB);
  __bf16* ob = (__bf16*)(ws + 32 * MB);
  __bf16* wqb = (__bf16*)(ws + 40 * MB);
  __bf16* wkb = (__bf16*)(ws + 42 * MB);
  __bf16* wvb = (__bf16*)(ws + 44 * MB);
  __bf16* wob = (__bf16*)(ws + 46 * MB);

  const int nx = M_ROWS * D;  // 4,194,304
  const int nw = D * D;       // 1,048,576

  cast_f32_bf16<<<nx / 4 / 256, 256, 0, stream>>>(x, xb);
  cast_w4<<<dim3(nw / 4 / 256, 4), 256, 0, stream>>>(Wq, Wk, Wv, Wo, wqb, wkb, wvb, wob);

  // fused QKV projection: 768 blocks = 3/CU
  gemm_bt<__bf16><<<dim3(D / 128, M_ROWS / 128, 3), 256, 0, stream>>>(
      xb, wqb, wkb, wvb, qb, kb, vb, D, D);

  attn_kernel<<<dim3(S / 128, BATCH * 16), 256, 0, stream>>>(qb, kb, vb, ob);

  gemm_bt<float><<<dim3(D / 128, M_ROWS / 128, 1), 256, 0, stream>>>(
      ob, wob, wob, wob, out, out, out, D, D);
}

// Round 5
// 189.957 us; speedup vs baseline: 1.8142x; 1.2014x over previous
//
#include <hip/hip_runtime.h>

typedef __attribute__((ext_vector_type(8))) __bf16 bf16x8;
typedef __attribute__((ext_vector_type(4))) __bf16 bf16x4;
typedef __attribute__((ext_vector_type(4))) float f32x4;

static constexpr int S = 2048;
static constexpr int D = 1024;
static constexpr int BATCH = 2;
static constexpr int M_ROWS = BATCH * S;  // 4096

#define GLOAD_LDS16(gp, lp)                                                        \
  __builtin_amdgcn_global_load_lds((const __attribute__((address_space(1))) void*)(gp), \
                                   (__attribute__((address_space(3))) void*)(lp), 16, 0, 0)

// ---------------- f32 -> bf16 casts ----------------
__global__ __launch_bounds__(256) void cast_f32_bf16(const float* __restrict__ in,
                                                     __bf16* __restrict__ out) {
  int i = (blockIdx.x * 256 + threadIdx.x) * 4;
  *reinterpret_cast<bf16x4*>(out + i) =
      __builtin_convertvector(*reinterpret_cast<const f32x4*>(in + i), bf16x4);
}

__global__ __launch_bounds__(256) void cast_w4(const float* __restrict__ w0, const float* __restrict__ w1,
                                               const float* __restrict__ w2, const float* __restrict__ w3,
                                               __bf16* __restrict__ o0, __bf16* __restrict__ o1,
                                               __bf16* __restrict__ o2, __bf16* __restrict__ o3) {
  const float* in = blockIdx.y == 0 ? w0 : blockIdx.y == 1 ? w1 : blockIdx.y == 2 ? w2 : w3;
  __bf16* out = blockIdx.y == 0 ? o0 : blockIdx.y == 1 ? o1 : blockIdx.y == 2 ? o2 : o3;
  int i = (blockIdx.x * 256 + threadIdx.x) * 4;
  *reinterpret_cast<bf16x4*>(out + i) =
      __builtin_convertvector(*reinterpret_cast<const f32x4*>(in + i), bf16x4);
}

// ---------------- GEMM core: C[m0:+128, n0:+128] = A[M,K] @ Bm[N,K]^T ----------------
// m97 structure: BK=32, 4 waves (2x2), global_load_lds width-16, linear LDS.
template <typename OutT>
__device__ __forceinline__ void gemm_core(const __bf16* __restrict__ A,
                                          const __bf16* __restrict__ Bm,
                                          OutT* __restrict__ C, int m0, int n0, int K, int ldc,
                                          __bf16* At, __bf16* Bt) {
  const int tid = threadIdx.x;
  const int w = tid >> 6, l = tid & 63;
  const int wr = w >> 1, wc = w & 1;
  const int ln = l & 15, gr = l >> 4;

  const int srow = w * 32 + (l >> 2);
  const int scol = (l & 3) * 8;
  const size_t aoff = (size_t)(m0 + srow) * K + scol;
  const size_t boff = (size_t)(n0 + srow) * K + scol;
  __bf16* lA = At + w * 2 * 512;
  __bf16* lB = Bt + w * 2 * 512;

  f32x4 acc[4][4] = {};

  for (int k0 = 0; k0 < K; k0 += 32) {
    __syncthreads();
    GLOAD_LDS16(A + aoff + k0, lA);
    GLOAD_LDS16(A + aoff + (size_t)16 * K + k0, lA + 512);
    GLOAD_LDS16(Bm + boff + k0, lB);
    GLOAD_LDS16(Bm + boff + (size_t)16 * K + k0, lB + 512);
    __syncthreads();

    bf16x8 af[4], bfr[4];
#pragma unroll
    for (int mi = 0; mi < 4; mi++)
      af[mi] = *reinterpret_cast<const bf16x8*>(&At[(wr * 64 + mi * 16 + ln) * 32 + gr * 8]);
#pragma unroll
    for (int ni = 0; ni < 4; ni++)
      bfr[ni] = *reinterpret_cast<const bf16x8*>(&Bt[(wc * 64 + ni * 16 + ln) * 32 + gr * 8]);
#pragma unroll
    for (int mi = 0; mi < 4; mi++)
#pragma unroll
      for (int ni = 0; ni < 4; ni++)
        acc[mi][ni] = __builtin_amdgcn_mfma_f32_16x16x32_bf16(af[mi], bfr[ni], acc[mi][ni], 0, 0, 0);
  }

#pragma unroll
  for (int mi = 0; mi < 4; mi++)
#pragma unroll
    for (int ni = 0; ni < 4; ni++)
#pragma unroll
      for (int r = 0; r < 4; r++) {
        int row = m0 + wr * 64 + mi * 16 + gr * 4 + r;
        int col = n0 + wc * 64 + ni * 16 + ln;
        float v = acc[mi][ni][r];
        if constexpr (__is_same(OutT, float))
          C[(size_t)row * ldc + col] = v;
        else
          C[(size_t)row * ldc + col] = (__bf16)v;
      }
}

// Fused QKV projection (768 blocks): Q = X Wq^T, K = X Wk^T, V^T = Wv X^T.
__global__ __launch_bounds__(256) void qkv_gemm(const __bf16* __restrict__ xb,
                                                const __bf16* __restrict__ wq,
                                                const __bf16* __restrict__ wk,
                                                const __bf16* __restrict__ wv,
                                                __bf16* __restrict__ q, __bf16* __restrict__ k,
                                                __bf16* __restrict__ vt) {
  __shared__ __bf16 At[128 * 32];
  __shared__ __bf16 Bt[128 * 32];
  const int id = blockIdx.x;
  const __bf16 *A, *B;
  __bf16* C;
  int m0, n0, ldc;
  if (id < 512) {  // Q or K: C[4096,1024] = xb @ W^T
    A = xb;
    B = (id < 256) ? wq : wk;
    C = (id < 256) ? q : k;
    int t = id & 255;
    m0 = (t >> 3) * 128;
    n0 = (t & 7) * 128;
    ldc = 1024;
  } else {  // V^T: C[1024,4096] = wv @ xb^T
    int t = id - 512;
    A = wv;
    B = xb;
    C = vt;
    m0 = (t & 7) * 128;
    n0 = (t >> 3) * 128;
    ldc = 4096;
  }
  gemm_core<__bf16>(A, B, C, m0, n0, 1024, ldc, At, Bt);
}

__global__ __launch_bounds__(256) void wo_gemm(const __bf16* __restrict__ ob,
                                               const __bf16* __restrict__ wo,
                                               float* __restrict__ out) {
  __shared__ __bf16 At[128 * 32];
  __shared__ __bf16 Bt[128 * 32];
  gemm_core<float>(ob, wo, out, blockIdx.y * 128, blockIdx.x * 128, 1024, 1024, At, Bt);
}

// ---------------- causal flash attention: barrier-free, 1 wave / 32 q-rows ----------------
// grid (S/32, B*H), block 64. Swapped-operand MFMAs:
//   S^T = mfma(K, Q)   -> lane holds S[q = m*16+ln][key = 16c+4gr+r]  (softmax lane-local in q)
//   O^T = mfma(V^T, P^T)-> lane holds O[q = m*16+ln][d = t*16+4gr+r]
// K read from global (L2-resident: 256KB/head); V via V^T global buffer (16B row loads).
// P relayout through a wave-private 2.5KB LDS tile (no barriers).
__global__ __launch_bounds__(64) void attn_kernel(const __bf16* __restrict__ Qb,
                                                  const __bf16* __restrict__ Kb,
                                                  const __bf16* __restrict__ VTb,
                                                  __bf16* __restrict__ Ob) {
  __shared__ __bf16 pt[32][40];  // [q][key], stride 40 elems: b64 writes 2-way, b128 reads conflict-free

  const int bh = blockIdx.y;
  const int b = bh >> 4, h = bh & 15;
  const int q0 = blockIdx.x * 32;
  const __bf16* Qp = Qb + (size_t)b * S * D + h * 64;
  const __bf16* Kp = Kb + (size_t)b * S * D + h * 64;
  const __bf16* Vt = VTb + (size_t)(h * 64) * M_ROWS + b * S;  // row d (stride 4096), col key

  const int l = threadIdx.x;
  const int ln = l & 15, gr = l >> 4;
  const float SCALE = 0.125f;  // 1/sqrt(64)
  const float NEG = -1e30f;

  bf16x8 qf[2][2];
#pragma unroll
  for (int m = 0; m < 2; m++)
#pragma unroll
    for (int s = 0; s < 2; s++)
      qf[m][s] = *reinterpret_cast<const bf16x8*>(
          Qp + (size_t)(q0 + m * 16 + ln) * D + s * 32 + gr * 8);

  f32x4 oacc[2][4] = {};
  float mr[2] = {NEG, NEG}, ls[2] = {0.f, 0.f};

#define LOADK(dst, kk)                                                            \
  _Pragma("unroll") for (int c = 0; c < 2; c++) _Pragma("unroll") for (int s = 0; s < 2; s++) \
      dst[c][s] = *reinterpret_cast<const bf16x8*>(                               \
          Kp + (size_t)((kk) + c * 16 + ln) * D + s * 32 + gr * 8);
#define LOADV(dst, kk)                                                            \
  _Pragma("unroll") for (int t = 0; t < 4; t++)                                   \
      dst[t] = *reinterpret_cast<const bf16x8*>(                                  \
          Vt + (size_t)(t * 16 + ln) * M_ROWS + (kk) + gr * 8);

  bf16x8 kf[2][2], vf[4];
  LOADK(kf, 0);
  LOADV(vf, 0);

  for (int k0 = 0; k0 <= q0; k0 += 32) {
    const bool tail = (k0 == q0);

    // ---- S^T = K Q^T ----
    f32x4 st[2][2] = {};  // [c][m]
#pragma unroll
    for (int c = 0; c < 2; c++)
#pragma unroll
      for (int m = 0; m < 2; m++) {
        st[c][m] = __builtin_amdgcn_mfma_f32_16x16x32_bf16(kf[c][0], qf[m][0], st[c][m], 0, 0, 0);
        st[c][m] = __builtin_amdgcn_mfma_f32_16x16x32_bf16(kf[c][1], qf[m][1], st[c][m], 0, 0, 0);
      }

    // ---- prefetch next K/V tile (hides under softmax+PV) ----
    bf16x8 kn[2][2], vn[4];
    if (k0 + 32 <= q0) {
      LOADK(kn, k0 + 32);
      LOADV(vn, k0 + 32);
    }

    // ---- softmax (per m: q = m*16+ln lane-local; row spread over 4 gr lanes) ----
    float al[2];
#pragma unroll
    for (int m = 0; m < 2; m++) {
      float pv[8];
      float tm = NEG;
#pragma unroll
      for (int c = 0; c < 2; c++)
#pragma unroll
        for (int r = 0; r < 4; r++) {
          float v = st[c][m][r] * SCALE;
          if (tail) v = (c * 16 + 4 * gr + r <= m * 16 + ln) ? v : NEG;
          pv[c * 4 + r] = v;
          tm = fmaxf(tm, v);
        }
      tm = fmaxf(tm, __shfl_xor(tm, 16));
      tm = fmaxf(tm, __shfl_xor(tm, 32));
      float nm = fmaxf(mr[m], tm);
      al[m] = __expf(mr[m] - nm);
      mr[m] = nm;
      float ps = 0.f;
#pragma unroll
      for (int i = 0; i < 8; i++) {
        pv[i] = __expf(pv[i] - nm);
        ps += pv[i];
      }
      ps += __shfl_xor(ps, 16);
      ps += __shfl_xor(ps, 32);
      ls[m] = ls[m] * al[m] + ps;
#pragma unroll
      for (int c = 0; c < 2; c++) {
        bf16x4 pk = {(__bf16)pv[c * 4 + 0], (__bf16)pv[c * 4 + 1],
                     (__bf16)pv[c * 4 + 2], (__bf16)pv[c * 4 + 3]};
        *reinterpret_cast<bf16x4*>(&pt[m * 16 + ln][c * 16 + 4 * gr]) = pk;
      }
    }

    // ---- O^T += V^T P^T ----
#pragma unroll
    for (int m = 0; m < 2; m++) {
      bf16x8 pp = *reinterpret_cast<const bf16x8*>(&pt[m * 16 + ln][gr * 8]);
#pragma unroll
      for (int t = 0; t < 4; t++) {
#pragma unroll
        for (int r = 0; r < 4; r++) oacc[m][t][r] *= al[m];
        oacc[m][t] = __builtin_amdgcn_mfma_f32_16x16x32_bf16(vf[t], pp, oacc[m][t], 0, 0, 0);
      }
    }

#pragma unroll
    for (int c = 0; c < 2; c++)
#pragma unroll
      for (int s = 0; s < 2; s++) kf[c][s] = kn[c][s];
#pragma unroll
    for (int t = 0; t < 4; t++) vf[t] = vn[t];
  }

  // ---- normalize + store (lane holds O[q=m*16+ln][d=t*16+4gr+r]) ----
#pragma unroll
  for (int m = 0; m < 2; m++) {
    float inv = 1.0f / ls[m];
    size_t row = (size_t)(b * S + q0 + m * 16 + ln);
#pragma unroll
    for (int t = 0; t < 4; t++) {
      bf16x4 ov = {(__bf16)(oacc[m][t][0] * inv), (__bf16)(oacc[m][t][1] * inv),
                   (__bf16)(oacc[m][t][2] * inv), (__bf16)(oacc[m][t][3] * inv)};
      *reinterpret_cast<bf16x4*>(Ob + row * D + h * 64 + t * 16 + gr * 4) = ov;
    }
  }
}

// ---------------- launcher ----------------
extern "C" void kernel_launch(void* const* d_in, const int* in_sizes, int n_in,
                              void* d_out, int out_size, void* d_ws, size_t ws_size,
                              hipStream_t stream) {
  const float* x = (const float*)d_in[0];
  const float* Wq = (const float*)d_in[1];
  const float* Wk = (const float*)d_in[2];
  const float* Wv = (const float*)d_in[3];
  const float* Wo = (const float*)d_in[4];
  float* out = (float*)d_out;

  char* ws = (char*)d_ws;
  const size_t MB = 1024 * 1024;
  __bf16* xb = (__bf16*)(ws + 0 * MB);
  __bf16* qb = (__bf16*)(ws + 8 * MB);
  __bf16* kb = (__bf16*)(ws + 16 * MB);
  __bf16* vtb = (__bf16*)(ws + 24 * MB);  // V^T [1024][4096]
  __bf16* ob = (__bf16*)(ws + 32 * MB);
  __bf16* wqb = (__bf16*)(ws + 40 * MB);
  __bf16* wkb = (__bf16*)(ws + 42 * MB);
  __bf16* wvb = (__bf16*)(ws + 44 * MB);
  __bf16* wob = (__bf16*)(ws + 46 * MB);

  const int nx = M_ROWS * D;  // 4,194,304
  const int nw = D * D;       // 1,048,576

  cast_f32_bf16<<<nx / 4 / 256, 256, 0, stream>>>(x, xb);
  cast_w4<<<dim3(nw / 4 / 256, 4), 256, 0, stream>>>(Wq, Wk, Wv, Wo, wqb, wkb, wvb, wob);

  qkv_gemm<<<768, 256, 0, stream>>>(xb, wqb, wkb, wvb, qb, kb, vtb);

  attn_kernel<<<dim3(S / 32, BATCH * 16), 64, 0, stream>>>(qb, kb, vtb, ob);

  wo_gemm<<<dim3(8, 32), 256, 0, stream>>>(ob, wob, out);
}

// Round 6
// 173.695 us; speedup vs baseline: 1.9840x; 1.0936x over previous
//
#include <hip/hip_runtime.h>

typedef __attribute__((ext_vector_type(8))) __bf16 bf16x8;
typedef __attribute__((ext_vector_type(4))) __bf16 bf16x4;
typedef __attribute__((ext_vector_type(4))) float f32x4;

static constexpr int S = 2048;
static constexpr int D = 1024;
static constexpr int BATCH = 2;
static constexpr int M_ROWS = BATCH * S;  // 4096

#define GLOAD_LDS16(gp, lp)                                                        \
  __builtin_amdgcn_global_load_lds((const __attribute__((address_space(1))) void*)(gp), \
                                   (__attribute__((address_space(3))) void*)(lp), 16, 0, 0)

// ---------------- f32 -> bf16 casts ----------------
__global__ __launch_bounds__(256) void cast_f32_bf16(const float* __restrict__ in,
                                                     __bf16* __restrict__ out) {
  int i = (blockIdx.x * 256 + threadIdx.x) * 4;
  *reinterpret_cast<bf16x4*>(out + i) =
      __builtin_convertvector(*reinterpret_cast<const f32x4*>(in + i), bf16x4);
}

__global__ __launch_bounds__(256) void cast_w4(const float* __restrict__ w0, const float* __restrict__ w1,
                                               const float* __restrict__ w2, const float* __restrict__ w3,
                                               __bf16* __restrict__ o0, __bf16* __restrict__ o1,
                                               __bf16* __restrict__ o2, __bf16* __restrict__ o3) {
  const float* in = blockIdx.y == 0 ? w0 : blockIdx.y == 1 ? w1 : blockIdx.y == 2 ? w2 : w3;
  __bf16* out = blockIdx.y == 0 ? o0 : blockIdx.y == 1 ? o1 : blockIdx.y == 2 ? o2 : o3;
  int i = (blockIdx.x * 256 + threadIdx.x) * 4;
  *reinterpret_cast<bf16x4*>(out + i) =
      __builtin_convertvector(*reinterpret_cast<const f32x4*>(in + i), bf16x4);
}

// ---------------- GEMM core: C[m0:+128, n0:+128] = A[M,K] @ Bm[N,K]^T ----------------
template <typename OutT>
__device__ __forceinline__ void gemm_core(const __bf16* __restrict__ A,
                                          const __bf16* __restrict__ Bm,
                                          OutT* __restrict__ C, int m0, int n0, int K, int ldc,
                                          __bf16* At, __bf16* Bt) {
  const int tid = threadIdx.x;
  const int w = tid >> 6, l = tid & 63;
  const int wr = w >> 1, wc = w & 1;
  const int ln = l & 15, gr = l >> 4;

  const int srow = w * 32 + (l >> 2);
  const int scol = (l & 3) * 8;
  const size_t aoff = (size_t)(m0 + srow) * K + scol;
  const size_t boff = (size_t)(n0 + srow) * K + scol;
  __bf16* lA = At + w * 2 * 512;
  __bf16* lB = Bt + w * 2 * 512;

  f32x4 acc[4][4] = {};

  for (int k0 = 0; k0 < K; k0 += 32) {
    __syncthreads();
    GLOAD_LDS16(A + aoff + k0, lA);
    GLOAD_LDS16(A + aoff + (size_t)16 * K + k0, lA + 512);
    GLOAD_LDS16(Bm + boff + k0, lB);
    GLOAD_LDS16(Bm + boff + (size_t)16 * K + k0, lB + 512);
    __syncthreads();

    bf16x8 af[4], bfr[4];
#pragma unroll
    for (int mi = 0; mi < 4; mi++)
      af[mi] = *reinterpret_cast<const bf16x8*>(&At[(wr * 64 + mi * 16 + ln) * 32 + gr * 8]);
#pragma unroll
    for (int ni = 0; ni < 4; ni++)
      bfr[ni] = *reinterpret_cast<const bf16x8*>(&Bt[(wc * 64 + ni * 16 + ln) * 32 + gr * 8]);
#pragma unroll
    for (int mi = 0; mi < 4; mi++)
#pragma unroll
      for (int ni = 0; ni < 4; ni++)
        acc[mi][ni] = __builtin_amdgcn_mfma_f32_16x16x32_bf16(af[mi], bfr[ni], acc[mi][ni], 0, 0, 0);
  }

#pragma unroll
  for (int mi = 0; mi < 4; mi++)
#pragma unroll
    for (int ni = 0; ni < 4; ni++)
#pragma unroll
      for (int r = 0; r < 4; r++) {
        int row = m0 + wr * 64 + mi * 16 + gr * 4 + r;
        int col = n0 + wc * 64 + ni * 16 + ln;
        float v = acc[mi][ni][r];
        if constexpr (__is_same(OutT, float))
          C[(size_t)row * ldc + col] = v;
        else
          C[(size_t)row * ldc + col] = (__bf16)v;
      }
}

// Fused QKV projection (768 blocks): Q = X Wq^T, K = X Wk^T, V^T = Wv X^T.
__global__ __launch_bounds__(256) void qkv_gemm(const __bf16* __restrict__ xb,
                                                const __bf16* __restrict__ wq,
                                                const __bf16* __restrict__ wk,
                                                const __bf16* __restrict__ wv,
                                                __bf16* __restrict__ q, __bf16* __restrict__ k,
                                                __bf16* __restrict__ vt) {
  __shared__ __bf16 At[128 * 32];
  __shared__ __bf16 Bt[128 * 32];
  const int id = blockIdx.x;
  const __bf16 *A, *B;
  __bf16* C;
  int m0, n0, ldc;
  if (id < 512) {  // Q or K: C[4096,1024] = xb @ W^T
    A = xb;
    B = (id < 256) ? wq : wk;
    C = (id < 256) ? q : k;
    int t = id & 255;
    m0 = (t >> 3) * 128;
    n0 = (t & 7) * 128;
    ldc = 1024;
  } else {  // V^T: C[1024,4096] = wv @ xb^T
    int t = id - 512;
    A = wv;
    B = xb;
    C = vt;
    m0 = (t & 7) * 128;
    n0 = (t >> 3) * 128;
    ldc = 4096;
  }
  gemm_core<__bf16>(A, B, C, m0, n0, 1024, ldc, At, Bt);
}

__global__ __launch_bounds__(256) void wo_gemm(const __bf16* __restrict__ ob,
                                               const __bf16* __restrict__ wo,
                                               float* __restrict__ out) {
  __shared__ __bf16 At[128 * 32];
  __shared__ __bf16 Bt[128 * 32];
  gemm_core<float>(ob, wo, out, blockIdx.y * 128, blockIdx.x * 128, 1024, 1024, At, Bt);
}

// ---------------- causal flash attention ----------------
// Barrier-free, 1 wave / 32 q-rows, software-pipelined:
//   iter t: QK^T(t+1) MFMAs issue first (inputs prefetched) -> overlap softmax(t) VALU -> PV(t).
// Swapped-operand MFMAs (S^T = mfma(K,Q), O^T = mfma(V^T,P^T)): softmax stats lane-local.
// defer-max (THR=8), exp2-domain softmax.
// Block remap: XCD-pinned (each XCD owns 4 heads -> K/V L2-resident) + longest-q-first.
__global__ __launch_bounds__(64) void attn_kernel(const __bf16* __restrict__ Qb,
                                                  const __bf16* __restrict__ Kb,
                                                  const __bf16* __restrict__ VTb,
                                                  __bf16* __restrict__ Ob) {
  __shared__ __bf16 pt[32][40];  // [q][key], stride 40: b64 writes 2-way (free), b128 reads clean

  // ---- block remap: lin -> (xcd-pinned contiguous work, longest q-tile first) ----
  const int lin = blockIdx.x + gridDim.x * blockIdx.y;   // 0..2047
  const int wid = ((lin & 7) << 8) | (lin >> 3);         // XCD k owns wid in [256k, 256k+256)
  const int bh = wid >> 6;                               // 4 heads per XCD
  const int b = bh >> 4, h = bh & 15;
  const int q0 = (63 - (wid & 63)) * 32;                 // longest-first within XCD

  const __bf16* Qp = Qb + (size_t)b * S * D + h * 64;
  const __bf16* Kp = Kb + (size_t)b * S * D + h * 64;
  const __bf16* Vt = VTb + (size_t)(h * 64) * M_ROWS + b * S;

  const int l = threadIdx.x;
  const int ln = l & 15, gr = l >> 4;
  const float SCALE2 = 0.125f * 1.44269504f;  // 1/sqrt(64) * log2(e)
  const float NEG = -1e30f;
  const int n = (q0 >> 5) + 1;  // number of 32-key tiles

  bf16x8 qf[2][2];
#pragma unroll
  for (int m = 0; m < 2; m++)
#pragma unroll
    for (int s = 0; s < 2; s++)
      qf[m][s] = *reinterpret_cast<const bf16x8*>(
          Qp + (size_t)(q0 + m * 16 + ln) * D + s * 32 + gr * 8);

  f32x4 oacc[2][4] = {};
  float mr[2] = {NEG, NEG}, ls[2] = {0.f, 0.f};

  auto loadK = [&](bf16x8 (&dst)[2][2], int kk) {
#pragma unroll
    for (int c = 0; c < 2; c++)
#pragma unroll
      for (int s = 0; s < 2; s++)
        dst[c][s] = *reinterpret_cast<const bf16x8*>(
            Kp + (size_t)(kk + c * 16 + ln) * D + s * 32 + gr * 8);
  };
  auto loadV = [&](bf16x8 (&dst)[4], int kk) {
#pragma unroll
    for (int t = 0; t < 4; t++)
      dst[t] = *reinterpret_cast<const bf16x8*>(
          Vt + (size_t)(t * 16 + ln) * M_ROWS + kk + gr * 8);
  };
  auto qk = [&](f32x4 (&st)[2][2], bf16x8 (&kf)[2][2]) {
#pragma unroll
    for (int c = 0; c < 2; c++)
#pragma unroll
      for (int m = 0; m < 2; m++) {
        f32x4 z = {};
        z = __builtin_amdgcn_mfma_f32_16x16x32_bf16(kf[c][0], qf[m][0], z, 0, 0, 0);
        z = __builtin_amdgcn_mfma_f32_16x16x32_bf16(kf[c][1], qf[m][1], z, 0, 0, 0);
        st[c][m] = z;
      }
  };
  // softmax(t) + PV(t). st layout: lane holds S[q=m*16+ln][key=16c+4gr+r].
  auto smpv = [&](f32x4 (&st)[2][2], bf16x8 (&vf)[4], int t) {
    const bool tail = (t == n - 1);
#pragma unroll
    for (int m = 0; m < 2; m++) {
      float pv[8];
      float tm = NEG;
#pragma unroll
      for (int c = 0; c < 2; c++)
#pragma unroll
        for (int r = 0; r < 4; r++) {
          float v = st[c][m][r] * SCALE2;
          if (tail) v = (c * 16 + 4 * gr + r <= m * 16 + ln) ? v : NEG;
          pv[c * 4 + r] = v;
          tm = fmaxf(tm, v);
        }
      tm = fmaxf(tm, __shfl_xor(tm, 16));
      tm = fmaxf(tm, __shfl_xor(tm, 32));
      // defer-max: only rescale when some row's max grew by > 8 (in log2 domain)
      if (!__all(tm - mr[m] <= 8.0f)) {
        float nm = fmaxf(mr[m], tm);
        float a = __builtin_exp2f(mr[m] - nm);
        mr[m] = nm;
        ls[m] *= a;
#pragma unroll
        for (int tt = 0; tt < 4; tt++)
#pragma unroll
          for (int r = 0; r < 4; r++) oacc[m][tt][r] *= a;
      }
      float ps = 0.f;
#pragma unroll
      for (int i = 0; i < 8; i++) {
        pv[i] = __builtin_exp2f(pv[i] - mr[m]);
        ps += pv[i];
      }
      ps += __shfl_xor(ps, 16);
      ps += __shfl_xor(ps, 32);
      ls[m] += ps;
#pragma unroll
      for (int c = 0; c < 2; c++) {
        bf16x4 pk = {(__bf16)pv[c * 4 + 0], (__bf16)pv[c * 4 + 1],
                     (__bf16)pv[c * 4 + 2], (__bf16)pv[c * 4 + 3]};
        *reinterpret_cast<bf16x4*>(&pt[m * 16 + ln][c * 16 + 4 * gr]) = pk;
      }
    }
#pragma unroll
    for (int m = 0; m < 2; m++) {
      bf16x8 pp = *reinterpret_cast<const bf16x8*>(&pt[m * 16 + ln][gr * 8]);
#pragma unroll
      for (int tt = 0; tt < 4; tt++)
        oacc[m][tt] = __builtin_amdgcn_mfma_f32_16x16x32_bf16(vf[tt], pp, oacc[m][tt], 0, 0, 0);
    }
  };

  // ---- pipelined main loop (manual 2-unroll, static register sets) ----
  f32x4 stA[2][2], stB[2][2];
  bf16x8 kf0[2][2], kf1[2][2], vf0[4], vf1[4];

  loadK(kf0, 0);
  loadV(vf0, 0);
  if (n > 1) {
    loadK(kf1, 32);
    loadV(vf1, 32);
  }
  qk(stA, kf0);  // st(0)

  auto iter_step = [&](f32x4 (&stCur)[2][2], f32x4 (&stNxt)[2][2],
                       bf16x8 (&kfNxt)[2][2], bf16x8 (&kfTgt)[2][2],
                       bf16x8 (&vfCur)[4], int t) {
    if (t + 1 < n) qk(stNxt, kfNxt);          // MFMA for t+1 overlaps softmax(t) below
    if (t + 2 < n) loadK(kfTgt, 32 * (t + 2));  // K(t) slot is dead; full-iter prefetch
    smpv(stCur, vfCur, t);
    if (t + 2 < n) loadV(vfCur, 32 * (t + 2));  // V(t) just consumed; ~2-iter prefetch
  };

  int t = 0;
  for (;;) {
    iter_step(stA, stB, kf1, kf0, vf0, t);  // even t
    if (++t >= n) break;
    iter_step(stB, stA, kf0, kf1, vf1, t);  // odd t
    if (++t >= n) break;
  }

  // ---- normalize + store (lane holds O[q=m*16+ln][d=tt*16+4gr+r]) ----
#pragma unroll
  for (int m = 0; m < 2; m++) {
    float inv = 1.0f / ls[m];
    size_t row = (size_t)(b * S + q0 + m * 16 + ln);
#pragma unroll
    for (int tt = 0; tt < 4; tt++) {
      bf16x4 ov = {(__bf16)(oacc[m][tt][0] * inv), (__bf16)(oacc[m][tt][1] * inv),
                   (__bf16)(oacc[m][tt][2] * inv), (__bf16)(oacc[m][tt][3] * inv)};
      *reinterpret_cast<bf16x4*>(Ob + row * D + h * 64 + tt * 16 + gr * 4) = ov;
    }
  }
}

// ---------------- launcher ----------------
extern "C" void kernel_launch(void* const* d_in, const int* in_sizes, int n_in,
                              void* d_out, int out_size, void* d_ws, size_t ws_size,
                              hipStream_t stream) {
  const float* x = (const float*)d_in[0];
  const float* Wq = (const float*)d_in[1];
  const float* Wk = (const float*)d_in[2];
  const float* Wv = (const float*)d_in[3];
  const float* Wo = (const float*)d_in[4];
  float* out = (float*)d_out;

  char* ws = (char*)d_ws;
  const size_t MB = 1024 * 1024;
  __bf16* xb = (__bf16*)(ws + 0 * MB);
  __bf16* qb = (__bf16*)(ws + 8 * MB);
  __bf16* kb = (__bf16*)(ws + 16 * MB);
  __bf16* vtb = (__bf16*)(ws + 24 * MB);  // V^T [1024][4096]
  __bf16* ob = (__bf16*)(ws + 32 * MB);
  __bf16* wqb = (__bf16*)(ws + 40 * MB);
  __bf16* wkb = (__bf16*)(ws + 42 * MB);
  __bf16* wvb = (__bf16*)(ws + 44 * MB);
  __bf16* wob = (__bf16*)(ws + 46 * MB);

  const int nx = M_ROWS * D;  // 4,194,304
  const int nw = D * D;       // 1,048,576

  cast_f32_bf16<<<nx / 4 / 256, 256, 0, stream>>>(x, xb);
  cast_w4<<<dim3(nw / 4 / 256, 4), 256, 0, stream>>>(Wq, Wk, Wv, Wo, wqb, wkb, wvb, wob);

  qkv_gemm<<<768, 256, 0, stream>>>(xb, wqb, wkb, wvb, qb, kb, vtb);

  attn_kernel<<<dim3(S / 32, BATCH * 16), 64, 0, stream>>>(qb, kb, vtb, ob);

  wo_gemm<<<dim3(8, 32), 256, 0, stream>>>(ob, wob, out);
}

// Round 8
// 149.600 us; speedup vs baseline: 2.3036x; 1.1611x over previous
//
#include <hip/hip_runtime.h>

typedef __attribute__((ext_vector_type(8))) __bf16 bf16x8;
typedef __attribute__((ext_vector_type(4))) __bf16 bf16x4;
typedef __attribute__((ext_vector_type(4))) float f32x4;

static constexpr int S = 2048;
static constexpr int D = 1024;
static constexpr int BATCH = 2;
static constexpr int M_ROWS = BATCH * S;  // 4096

#define GLOAD_LDS16(gp, lp)                                                        \
  __builtin_amdgcn_global_load_lds((const __attribute__((address_space(1))) void*)(gp), \
                                   (__attribute__((address_space(3))) void*)(lp), 16, 0, 0)

// ---------------- f32 -> bf16 casts ----------------
__global__ __launch_bounds__(256) void cast_f32_bf16(const float* __restrict__ in,
                                                     __bf16* __restrict__ out) {
  int i = (blockIdx.x * 256 + threadIdx.x) * 4;
  *reinterpret_cast<bf16x4*>(out + i) =
      __builtin_convertvector(*reinterpret_cast<const f32x4*>(in + i), bf16x4);
}

__global__ __launch_bounds__(256) void cast_w4(const float* __restrict__ w0, const float* __restrict__ w1,
                                               const float* __restrict__ w2, const float* __restrict__ w3,
                                               __bf16* __restrict__ o0, __bf16* __restrict__ o1,
                                               __bf16* __restrict__ o2, __bf16* __restrict__ o3) {
  const float* in = blockIdx.y == 0 ? w0 : blockIdx.y == 1 ? w1 : blockIdx.y == 2 ? w2 : w3;
  __bf16* out = blockIdx.y == 0 ? o0 : blockIdx.y == 1 ? o1 : blockIdx.y == 2 ? o2 : o3;
  int i = (blockIdx.x * 256 + threadIdx.x) * 4;
  *reinterpret_cast<bf16x4*>(out + i) =
      __builtin_convertvector(*reinterpret_cast<const f32x4*>(in + i), bf16x4);
}

// ---------------- GEMM core: C[m0:+128, n0:+128] = A[M,K] @ Bm[N,K]^T ----------------
template <typename OutT>
__device__ __forceinline__ void gemm_core(const __bf16* __restrict__ A,
                                          const __bf16* __restrict__ Bm,
                                          OutT* __restrict__ C, int m0, int n0, int K, int ldc,
                                          __bf16* At, __bf16* Bt) {
  const int tid = threadIdx.x;
  const int w = tid >> 6, l = tid & 63;
  const int wr = w >> 1, wc = w & 1;
  const int ln = l & 15, gr = l >> 4;

  const int srow = w * 32 + (l >> 2);
  const int scol = (l & 3) * 8;
  const size_t aoff = (size_t)(m0 + srow) * K + scol;
  const size_t boff = (size_t)(n0 + srow) * K + scol;
  __bf16* lA = At + w * 2 * 512;
  __bf16* lB = Bt + w * 2 * 512;

  f32x4 acc[4][4] = {};

  for (int k0 = 0; k0 < K; k0 += 32) {
    __syncthreads();
    GLOAD_LDS16(A + aoff + k0, lA);
    GLOAD_LDS16(A + aoff + (size_t)16 * K + k0, lA + 512);
    GLOAD_LDS16(Bm + boff + k0, lB);
    GLOAD_LDS16(Bm + boff + (size_t)16 * K + k0, lB + 512);
    __syncthreads();

    bf16x8 af[4], bfr[4];
#pragma unroll
    for (int mi = 0; mi < 4; mi++)
      af[mi] = *reinterpret_cast<const bf16x8*>(&At[(wr * 64 + mi * 16 + ln) * 32 + gr * 8]);
#pragma unroll
    for (int ni = 0; ni < 4; ni++)
      bfr[ni] = *reinterpret_cast<const bf16x8*>(&Bt[(wc * 64 + ni * 16 + ln) * 32 + gr * 8]);
#pragma unroll
    for (int mi = 0; mi < 4; mi++)
#pragma unroll
      for (int ni = 0; ni < 4; ni++)
        acc[mi][ni] = __builtin_amdgcn_mfma_f32_16x16x32_bf16(af[mi], bfr[ni], acc[mi][ni], 0, 0, 0);
  }

#pragma unroll
  for (int mi = 0; mi < 4; mi++)
#pragma unroll
    for (int ni = 0; ni < 4; ni++)
#pragma unroll
      for (int r = 0; r < 4; r++) {
        int row = m0 + wr * 64 + mi * 16 + gr * 4 + r;
        int col = n0 + wc * 64 + ni * 16 + ln;
        float v = acc[mi][ni][r];
        if constexpr (__is_same(OutT, float))
          C[(size_t)row * ldc + col] = v;
        else
          C[(size_t)row * ldc + col] = (__bf16)v;
      }
}

// Fused QKV projection (768 blocks): Q = X Wq^T, K = X Wk^T, V^T = Wv X^T.
__global__ __launch_bounds__(256) void qkv_gemm(const __bf16* __restrict__ xb,
                                                const __bf16* __restrict__ wq,
                                                const __bf16* __restrict__ wk,
                                                const __bf16* __restrict__ wv,
                                                __bf16* __restrict__ q, __bf16* __restrict__ k,
                                                __bf16* __restrict__ vt) {
  __shared__ __bf16 At[128 * 32];
  __shared__ __bf16 Bt[128 * 32];
  const int id = blockIdx.x;
  const __bf16 *A, *B;
  __bf16* C;
  int m0, n0, ldc;
  if (id < 512) {  // Q or K: C[4096,1024] = xb @ W^T
    A = xb;
    B = (id < 256) ? wq : wk;
    C = (id < 256) ? q : k;
    int t = id & 255;
    m0 = (t >> 3) * 128;
    n0 = (t & 7) * 128;
    ldc = 1024;
  } else {  // V^T: C[1024,4096] = wv @ xb^T
    int t = id - 512;
    A = wv;
    B = xb;
    C = vt;
    m0 = (t & 7) * 128;
    n0 = (t >> 3) * 128;
    ldc = 4096;
  }
  gemm_core<__bf16>(A, B, C, m0, n0, 1024, ldc, At, Bt);
}

__global__ __launch_bounds__(256) void wo_gemm(const __bf16* __restrict__ ob,
                                               const __bf16* __restrict__ wo,
                                               float* __restrict__ out) {
  __shared__ __bf16 At[128 * 32];
  __shared__ __bf16 Bt[128 * 32];
  gemm_core<float>(ob, wo, out, blockIdx.y * 128, blockIdx.x * 128, 1024, 1024, At, Bt);
}

// ---------------- causal flash attention ----------------
// 256 blocks x 512 threads = 1 block/CU, 8 independent waves (2/SIMD guaranteed).
// Wave w owns one 32-row q-tile; tiles paired long+short so every SIMD gets
// exactly 65 k-iterations and every CU an identical 260-iteration workload.
// Software pipeline per wave: QK^T(t+1) issues before softmax(t) -> MFMA/VALU overlap.
// Swapped-operand MFMAs; defer-max (THR=8 in log2 domain); exp2 softmax.
// XCD-pinned: each XCD owns 4 heads (K/V L2-resident).
__global__ __launch_bounds__(512) void attn_kernel(const __bf16* __restrict__ Qb,
                                                   const __bf16* __restrict__ Kb,
                                                   const __bf16* __restrict__ VTb,
                                                   __bf16* __restrict__ Ob) {
  __shared__ __bf16 pt_all[8][32][40];  // per-wave P tile [q][key], stride 40

  const int lin = blockIdx.x;                      // 0..255
  const int wid = ((lin & 7) << 5) | (lin >> 3);   // XCD k owns wid in [32k, 32k+32)
  const int bh = wid >> 3;                         // 4 heads per XCD
  const int j = wid & 7;
  const int b = bh >> 4, h = bh & 15;

  const int tid = threadIdx.x;
  const int w = tid >> 6, l = tid & 63;
  const int ln = l & 15, gr = l >> 4;

  // per-SIMD balanced tile assignment: (w, w+4) pairs sum to 65 iterations
  int qt;
  switch (w) {
    case 0: qt = j; break;
    case 1: qt = 16 + j; break;
    case 2: qt = 15 - j; break;
    case 3: qt = 31 - j; break;
    case 4: qt = 63 - j; break;
    case 5: qt = 47 - j; break;
    case 6: qt = 48 + j; break;
    default: qt = 32 + j; break;
  }
  const int q0 = qt * 32;
  const int n = qt + 1;  // number of 32-key tiles

  const __bf16* Qp = Qb + (size_t)b * S * D + h * 64;
  const __bf16* Kp = Kb + (size_t)b * S * D + h * 64;
  const __bf16* Vt = VTb + (size_t)(h * 64) * M_ROWS + b * S;
  __bf16 (*pt)[40] = pt_all[w];

  const float SCALE2 = 0.125f * 1.44269504f;  // 1/sqrt(64) * log2(e)
  const float NEG = -1e30f;

  bf16x8 qf[2][2];
#pragma unroll
  for (int m = 0; m < 2; m++)
#pragma unroll
    for (int s = 0; s < 2; s++)
      qf[m][s] = *reinterpret_cast<const bf16x8*>(
          Qp + (size_t)(q0 + m * 16 + ln) * D + s * 32 + gr * 8);

  f32x4 oacc[2][4] = {};
  float mr[2] = {NEG, NEG}, ls[2] = {0.f, 0.f};

  auto loadK = [&](bf16x8 (&dst)[2][2], int kk) {
#pragma unroll
    for (int c = 0; c < 2; c++)
#pragma unroll
      for (int s = 0; s < 2; s++)
        dst[c][s] = *reinterpret_cast<const bf16x8*>(
            Kp + (size_t)(kk + c * 16 + ln) * D + s * 32 + gr * 8);
  };
  auto loadV = [&](bf16x8 (&dst)[4], int kk) {
#pragma unroll
    for (int t = 0; t < 4; t++)
      dst[t] = *reinterpret_cast<const bf16x8*>(
          Vt + (size_t)(t * 16 + ln) * M_ROWS + kk + gr * 8);
  };
  auto qk = [&](f32x4 (&st)[2][2], bf16x8 (&kf)[2][2]) {
    __builtin_amdgcn_s_setprio(1);
#pragma unroll
    for (int c = 0; c < 2; c++)
#pragma unroll
      for (int m = 0; m < 2; m++) {
        f32x4 z = {};
        z = __builtin_amdgcn_mfma_f32_16x16x32_bf16(kf[c][0], qf[m][0], z, 0, 0, 0);
        z = __builtin_amdgcn_mfma_f32_16x16x32_bf16(kf[c][1], qf[m][1], z, 0, 0, 0);
        st[c][m] = z;
      }
    __builtin_amdgcn_s_setprio(0);
  };
  // softmax(t) + PV(t). st layout: lane holds S[q=m*16+ln][key=16c+4gr+r].
  auto smpv = [&](f32x4 (&st)[2][2], bf16x8 (&vf)[4], int t) {
    const bool tail = (t == n - 1);
#pragma unroll
    for (int m = 0; m < 2; m++) {
      float pv[8];
      float tm = NEG;
#pragma unroll
      for (int c = 0; c < 2; c++)
#pragma unroll
        for (int r = 0; r < 4; r++) {
          float v = st[c][m][r] * SCALE2;
          if (tail) v = (c * 16 + 4 * gr + r <= m * 16 + ln) ? v : NEG;
          pv[c * 4 + r] = v;
          tm = fmaxf(tm, v);
        }
      tm = fmaxf(tm, __shfl_xor(tm, 16));
      tm = fmaxf(tm, __shfl_xor(tm, 32));
      // defer-max: only rescale when some row's max grew by > 8 (log2 domain)
      if (!__all(tm - mr[m] <= 8.0f)) {
        float nm = fmaxf(mr[m], tm);
        float a = __builtin_exp2f(mr[m] - nm);
        mr[m] = nm;
        ls[m] *= a;
#pragma unroll
        for (int tt = 0; tt < 4; tt++)
#pragma unroll
          for (int r = 0; r < 4; r++) oacc[m][tt][r] *= a;
      }
      float ps = 0.f;
#pragma unroll
      for (int i = 0; i < 8; i++) {
        pv[i] = __builtin_exp2f(pv[i] - mr[m]);
        ps += pv[i];
      }
      ps += __shfl_xor(ps, 16);
      ps += __shfl_xor(ps, 32);
      ls[m] += ps;
#pragma unroll
      for (int c = 0; c < 2; c++) {
        bf16x4 pk = {(__bf16)pv[c * 4 + 0], (__bf16)pv[c * 4 + 1],
                     (__bf16)pv[c * 4 + 2], (__bf16)pv[c * 4 + 3]};
        *reinterpret_cast<bf16x4*>(&pt[m * 16 + ln][c * 16 + 4 * gr]) = pk;
      }
    }
    __builtin_amdgcn_s_setprio(1);
#pragma unroll
    for (int m = 0; m < 2; m++) {
      bf16x8 pp = *reinterpret_cast<const bf16x8*>(&pt[m * 16 + ln][gr * 8]);
#pragma unroll
      for (int tt = 0; tt < 4; tt++)
        oacc[m][tt] = __builtin_amdgcn_mfma_f32_16x16x32_bf16(vf[tt], pp, oacc[m][tt], 0, 0, 0);
    }
    __builtin_amdgcn_s_setprio(0);
  };

  // ---- pipelined main loop (manual 2-unroll, static register sets) ----
  f32x4 stA[2][2], stB[2][2];
  bf16x8 kf0[2][2], kf1[2][2], vf0[4], vf1[4];

  loadK(kf0, 0);
  loadV(vf0, 0);
  if (n > 1) {
    loadK(kf1, 32);
    loadV(vf1, 32);
  }
  qk(stA, kf0);  // st(0)

  auto iter_step = [&](f32x4 (&stCur)[2][2], f32x4 (&stNxt)[2][2],
                       bf16x8 (&kfNxt)[2][2], bf16x8 (&kfTgt)[2][2],
                       bf16x8 (&vfCur)[4], int t) {
    if (t + 1 < n) qk(stNxt, kfNxt);            // MFMA for t+1 overlaps softmax(t)
    if (t + 2 < n) loadK(kfTgt, 32 * (t + 2));  // K(t) slot dead; full-iter prefetch
    smpv(stCur, vfCur, t);
    if (t + 2 < n) loadV(vfCur, 32 * (t + 2));  // V(t) consumed; ~2-iter prefetch
  };

  int t = 0;
  for (;;) {
    iter_step(stA, stB, kf1, kf0, vf0, t);  // even t
    if (++t >= n) break;
    iter_step(stB, stA, kf0, kf1, vf1, t);  // odd t
    if (++t >= n) break;
  }

  // ---- normalize + store (lane holds O[q=m*16+ln][d=tt*16+4gr+r]) ----
#pragma unroll
  for (int m = 0; m < 2; m++) {
    float inv = 1.0f / ls[m];
    size_t row = (size_t)(b * S + q0 + m * 16 + ln);
#pragma unroll
    for (int tt = 0; tt < 4; tt++) {
      bf16x4 ov = {(__bf16)(oacc[m][tt][0] * inv), (__bf16)(oacc[m][tt][1] * inv),
                   (__bf16)(oacc[m][tt][2] * inv), (__bf16)(oacc[m][tt][3] * inv)};
      *reinterpret_cast<bf16x4*>(Ob + row * D + h * 64 + tt * 16 + gr * 4) = ov;
    }
  }
}

// ---------------- launcher ----------------
extern "C" void kernel_launch(void* const* d_in, const int* in_sizes, int n_in,
                              void* d_out, int out_size, void* d_ws, size_t ws_size,
                              hipStream_t stream) {
  const float* x = (const float*)d_in[0];
  const float* Wq = (const float*)d_in[1];
  const float* Wk = (const float*)d_in[2];
  const float* Wv = (const float*)d_in[3];
  const float* Wo = (const float*)d_in[4];
  float* out = (float*)d_out;

  char* ws = (char*)d_ws;
  const size_t MB = 1024 * 1024;
  __bf16* xb = (__bf16*)(ws + 0 * MB);
  __bf16* qb = (__bf16*)(ws + 8 * MB);
  __bf16* kb = (__bf16*)(ws + 16 * MB);
  __bf16* vtb = (__bf16*)(ws + 24 * MB);  // V^T [1024][4096]
  __bf16* ob = (__bf16*)(ws + 32 * MB);
  __bf16* wqb = (__bf16*)(ws + 40 * MB);
  __bf16* wkb = (__bf16*)(ws + 42 * MB);
  __bf16* wvb = (__bf16*)(ws + 44 * MB);
  __bf16* wob = (__bf16*)(ws + 46 * MB);

  const int nx = M_ROWS * D;  // 4,194,304
  const int nw = D * D;       // 1,048,576

  cast_f32_bf16<<<nx / 4 / 256, 256, 0, stream>>>(x, xb);
  cast_w4<<<dim3(nw / 4 / 256, 4), 256, 0, stream>>>(Wq, Wk, Wv, Wo, wqb, wkb, wvb, wob);

  qkv_gemm<<<768, 256, 0, stream>>>(xb, wqb, wkb, wvb, qb, kb, vtb);

  attn_kernel<<<256, 512, 0, stream>>>(qb, kb, vtb, ob);

  wo_gemm<<<dim3(8, 32), 256, 0, stream>>>(ob, wob, out);
}